// Round 3
// baseline (342.163 us; speedup 1.0000x reference)
//
#include <hip/hip_runtime.h>

#define NBINS 50
#define PAD_G 100
#define TPB 256
#define GRID 2048      // 8 blocks/CU * 256 CUs; launch_bounds(256,8) -> VGPR<=64
#define STEPS 12       // bulk chunks per thread: 2048*256*12*4 = 25,165,824 elems

typedef float vf4 __attribute__((ext_vector_type(4)));

// Gaussian kernel (5 taps, sigma=0.5), normalized
#define K0 2.6387004e-4f
#define K1 1.0645079e-1f
#define K2 7.8657085e-1f

// element stride per pipeline step = GRID*TPB*4 = 2,097,152 = 41,943*50 + 2
#define DF 41943
#define DJ 2

__device__ __forceinline__ int quant(int g) {
  int d = g - 50;
  d = (d < 0) ? 0 : d;
  int q = __umul24((unsigned)d, 10923u) >> 16;  // exact /6 for this range
  return (q > NBINS - 1) ? (NBINS - 1) : q;
}

__device__ __forceinline__ float softplus_stable(float x) {
  return fmaxf(x, 0.f) + __logf(1.f + __expf(-fabsf(x)));
}

// qv2[f]: low byte = code(frame f), high byte = code(frame f+1); 255 = padded.
// Also accumulates #non-pad frames into acc[1] (mask.sum() == 50 * that).
__global__ __launch_bounds__(256) void pitch_pre(
    const int* __restrict__ gt, unsigned short* __restrict__ qv2, int n,
    float* __restrict__ acc)
{
  const int f = blockIdx.x * blockDim.x + threadIdx.x;
  if (f >= n) return;
  const int g0 = gt[f];
  const int f1 = (f + 1 < n) ? f + 1 : n - 1;
  const int g1 = gt[f1];
  const unsigned b0 = (g0 == PAD_G) ? 255u : (unsigned)quant(g0);
  const unsigned b1 = (g1 == PAD_G) ? 255u : (unsigned)quant(g1);
  qv2[f] = (unsigned short)(b0 | (b1 << 8));
  const unsigned long long ball = __ballot(g0 != PAD_G);
  if ((threadIdx.x & 63) == 0)
    atomicAdd((unsigned*)&acc[1], (unsigned)__popcll(ball));
}

// s_tab layout: 51 rows x 8 cols. Row q (q<50): col d1 holds the blur weight
// for output bin j = q - 2 + (d1-1); cols 0,6,7 are zero. Row 50 is all zero
// (absorbs pad code 255). Lookup: clamp(j - c + 3, 0, 7); out-of-range taps
// land on zero entries, no extra range compare needed.
__device__ __forceinline__ void consume_chunk(
    vf4 p, unsigned q2, int j0, const float* s_tab, float& num)
{
  const unsigned c0 = q2 & 255u;
  const unsigned c1 = q2 >> 8;
#pragma unroll
  for (int u = 0; u < 4; ++u) {
    int j = j0 + u;
    const bool wrap = (j >= NBINS);
    const unsigned c = wrap ? c1 : c0;
    j = wrap ? j - NBINS : j;
    const float x = p[u];
    const float sp = softplus_stable(x);
    const unsigned qc = (c > 50u) ? 50u : c;   // 255 -> zero row
    int dj = j - (int)c + 3;                   // tap offset +2, bias +1
    dj = dj < 0 ? 0 : (dj > 7 ? 7 : dj);
    const float t = s_tab[(qc << 3) + dj];
    const float spv = (c != 255u) ? sp : 0.f;  // pad frames contribute nothing
    num += __builtin_fmaf(-x, t, spv);
  }
}

__global__ __launch_bounds__(TPB, 8) void pitch_loss_main(
    const vf4* __restrict__ preds4,
    const unsigned short* __restrict__ qv2,
    int nvec, int total, int nblocks,
    float* __restrict__ acc,     // [0]=num(float) [1]=nvalid(uint) [2]=ctr(uint)
    float* __restrict__ out)
{
  __shared__ float s_tab[51 * 8];
  for (int idx = threadIdx.x; idx < 51 * 8; idx += TPB) {
    const int q = idx >> 3;
    const int dt = (idx & 7) - 1;        // tap offset in [-1..6]; valid 0..4
    float t = 0.f;
    if (q < NBINS && 0 <= dt && dt < 5) {
      const int j = q - 2 + dt;
      if (0 <= j && j < NBINS) {
        const float kk[5] = {K0, K1, K2, K1, K0};
#pragma unroll
        for (int i = 0; i < 5; ++i) {
          int m = j - 2 + i;
          m = (m < 0) ? -m : m;
          m = (m > NBINS - 1) ? 2 * (NBINS - 1) - m : m;
          if (m == q) t += kk[i];
        }
      }
    }
    s_tab[idx] = t;
  }
  __syncthreads();

  const int tid = blockIdx.x * TPB + threadIdx.x;
  const int nthreads = nblocks * TPB;
  float num = 0.f;

  // --- explicit 4-slot register pipeline, 3 steps in flight ---------------
  // R2 post-mortem: the compiler does NOT software-pipeline loads across
  // iterations (each iter's loads issued after previous consumes -> full
  // memory latency every 4 chunks, 132us). Hand pipeline with vmcnt ladder
  // (the structure that measured 88us) + no LDS staging + 8 blocks/CU.
  vf4 pp[4];
  unsigned qq[4];
  int jj[4];

  // incremental frame walker: e_{s+1} = e_s + 2,097,152 -> f += 41943(+c),
  // j0 = (j0+2) mod 50. Replaces per-step magic division.
  const int e0 = tid << 2;
  unsigned f = (unsigned)e0 / 50u;
  int j0 = e0 - (int)f * 50;
  int vs = tid;

  const int bulk = STEPS * nthreads;
  if (nvec >= bulk) {
    auto STAGE = [&](int b) {
      pp[b] = preds4[vs];            // global_load_dwordx4
      qq[b] = qv2[f];                // global_load_ushort
      jj[b] = j0;
      vs += nthreads;
      j0 += DJ;
      const unsigned carry = (j0 >= NBINS) ? 1u : 0u;
      j0 = (j0 >= NBINS) ? j0 - NBINS : j0;
      f += (unsigned)DF + carry;
    };
    STAGE(0); STAGE(1); STAGE(2);
#pragma unroll
    for (int s = 0; s < STEPS; ++s) {
      const int b = s & 3;
      if (s + 3 < STEPS) {
        STAGE((s + 3) & 3);
        // 3 younger groups (6 vmem) in flight; group s drained
        asm volatile("s_waitcnt vmcnt(6)" ::: "memory");
      } else if (s + 2 < STEPS) {
        asm volatile("s_waitcnt vmcnt(4)" ::: "memory");
      } else if (s + 1 < STEPS) {
        asm volatile("s_waitcnt vmcnt(2)" ::: "memory");
      } else {
        asm volatile("s_waitcnt vmcnt(0)" ::: "memory");
      }
      consume_chunk(pp[b], qq[b], jj[b], s_tab, num);
    }
  }

  // vector remainder: 262,144 chunks at this shape (half the threads do 1)
  const int start = (nvec >= bulk) ? bulk : 0;
  for (int v = start + tid; v < nvec; v += nthreads) {
    const vf4 p = preds4[v];
    const int e = v << 2;
    const unsigned ff = (unsigned)e / 50u;
    consume_chunk(p, qv2[ff], e - (int)ff * 50, s_tab, num);
  }
  // scalar element tail (total % 4 != 0; empty at this shape)
  for (int e = (nvec << 2) + tid; e < total; e += nthreads) {
    const unsigned ff = (unsigned)e / 50u;
    const int j = e - (int)ff * 50;
    const unsigned c = qv2[ff] & 255u;
    const float x = ((const float*)preds4)[e];
    const unsigned qc = (c > 50u) ? 50u : c;
    int dj = j - (int)c + 3;
    dj = dj < 0 ? 0 : (dj > 7 ? 7 : dj);
    const float t = s_tab[(qc << 3) + dj];
    const float spv = (c != 255u) ? softplus_stable(x) : 0.f;
    num += __builtin_fmaf(-x, t, spv);
  }

  // wave-64 reduction, then one atomic per block
  const int wave = threadIdx.x >> 6;
  const int lane = threadIdx.x & 63;
#pragma unroll
  for (int off = 32; off > 0; off >>= 1)
    num += __shfl_down(num, off, 64);
  __shared__ float sn[TPB / 64];
  if (lane == 0) sn[wave] = num;
  __syncthreads();
  if (threadIdx.x == 0) {
    const float n = sn[0] + sn[1] + sn[2] + sn[3];
    atomicAdd(&acc[0], n);
    __threadfence();
    const unsigned done = atomicAdd((unsigned*)&acc[2], 1u);
    if (done == (unsigned)nblocks - 1u) {
      const float tn = atomicAdd(&acc[0], 0.f);
      const unsigned nvalid = atomicAdd((unsigned*)&acc[1], 0u);
      out[0] = tn / (50.0f * (float)nvalid);
    }
  }
}

extern "C" void kernel_launch(void* const* d_in, const int* in_sizes, int n_in,
                              void* d_out, int out_size, void* d_ws, size_t ws_size,
                              hipStream_t stream) {
  const vf4* preds4 = (const vf4*)d_in[0];
  const int* gt = (const int*)d_in[1];
  float* out = (float*)d_out;
  float* acc = (float*)d_ws;                                   // 12 B
  unsigned short* qv2 = (unsigned short*)((char*)d_ws + 256);  // 1 MB
  const int total = in_sizes[0];     // 26214400
  const int nframes = in_sizes[1];   // 524288
  const int nvec = total >> 2;       // 6553600

  (void)hipMemsetAsync(acc, 0, 3 * sizeof(float), stream);

  pitch_pre<<<(nframes + 255) / 256, 256, 0, stream>>>(gt, qv2, nframes, acc);

  pitch_loss_main<<<GRID, TPB, 0, stream>>>(
      preds4, qv2, nvec, total, GRID, acc, out);
}

// Round 4
// 323.242 us; speedup vs baseline: 1.0585x; 1.0585x over previous
//
#include <hip/hip_runtime.h>

#define NBINS 50
#define PAD_G 100
#define TPB 256
#define GRID 2048      // 8 blocks/CU * 256 CUs; LDS 18KB -> exactly 8 resident
#define STEPS 12       // bulk chunks: 2048*256*12 = 6,291,456 of 6,553,600
#define PIPE 4         // wave-private LDS slots; 3 steps in flight

typedef float vf4 __attribute__((ext_vector_type(4)));

// Gaussian kernel (5 taps, sigma=0.5), normalized
#define K0 2.6387004e-4f
#define K1 1.0645079e-1f
#define K2 7.8657085e-1f

// element stride per pipeline step = GRID*TPB*4 = 2,097,152 = 41,943*50 + 2
#define DF 41943
#define DJ 2

__device__ __forceinline__ int quant(int g) {
  int d = g - 50;
  d = (d < 0) ? 0 : d;
  int q = __umul24((unsigned)d, 10923u) >> 16;  // exact /6 for this range
  return (q > NBINS - 1) ? (NBINS - 1) : q;
}

__device__ __forceinline__ float softplus_stable(float x) {
  return fmaxf(x, 0.f) + __logf(1.f + __expf(-fabsf(x)));
}

// qv2[f]: low byte = code(frame f), high byte = code(frame f+1); 255 = padded.
// Also accumulates #non-pad frames into acc[1] (mask.sum() == 50 * that).
__global__ __launch_bounds__(256) void pitch_pre(
    const int* __restrict__ gt, unsigned short* __restrict__ qv2, int n,
    float* __restrict__ acc)
{
  const int f = blockIdx.x * blockDim.x + threadIdx.x;
  if (f >= n) return;
  const int g0 = gt[f];
  const int f1 = (f + 1 < n) ? f + 1 : n - 1;
  const int g1 = gt[f1];
  const unsigned b0 = (g0 == PAD_G) ? 255u : (unsigned)quant(g0);
  const unsigned b1 = (g1 == PAD_G) ? 255u : (unsigned)quant(g1);
  qv2[f] = (unsigned short)(b0 | (b1 << 8));
  const unsigned long long ball = __ballot(g0 != PAD_G);
  if ((threadIdx.x & 63) == 0)
    atomicAdd((unsigned*)&acc[1], (unsigned)__popcll(ball));
}

// s_tab layout: 51 rows x 8 cols. Row q (q<50): col d1 holds the blur weight
// for output bin j = q - 2 + (d1-1); cols 0,6,7 are zero. Row 50 is all zero
// (absorbs pad code 255). Lookup: clamp(j - c + 3, 0, 7); out-of-range taps
// land on zero entries, no extra range compare needed.
__device__ __forceinline__ void consume_chunk(
    vf4 p, unsigned q2, int j0, const float* s_tab, float& num)
{
  const unsigned c0 = q2 & 255u;
  const unsigned c1 = q2 >> 8;
#pragma unroll
  for (int u = 0; u < 4; ++u) {
    int j = j0 + u;
    const bool wrap = (j >= NBINS);
    const unsigned c = wrap ? c1 : c0;
    j = wrap ? j - NBINS : j;
    const float x = p[u];
    const float sp = softplus_stable(x);
    const unsigned qc = (c > 50u) ? 50u : c;   // 255 -> zero row
    int dj = j - (int)c + 3;                   // tap offset +2, bias +1
    dj = dj < 0 ? 0 : (dj > 7 ? 7 : dj);
    const float t = s_tab[(qc << 3) + dj];
    const float spv = (c != 255u) ? sp : 0.f;  // pad frames contribute nothing
    num += __builtin_fmaf(-x, t, spv);
  }
}

__global__ __launch_bounds__(TPB, 8) void pitch_loss_main(
    const vf4* __restrict__ preds4,
    const unsigned short* __restrict__ qv2,
    int nvec, int total, int nblocks,
    float* __restrict__ acc,     // [0]=num(float) [1]=nvalid(uint) [2]=ctr(uint)
    float* __restrict__ out)
{
  __shared__ vf4 buf[PIPE][TPB];     // 4 x 4KB, wave-private 1KB quarters
  __shared__ float s_tab[51 * 8];

  for (int idx = threadIdx.x; idx < 51 * 8; idx += TPB) {
    const int q = idx >> 3;
    const int dt = (idx & 7) - 1;        // tap offset in [-1..6]; valid 0..4
    float t = 0.f;
    if (q < NBINS && 0 <= dt && dt < 5) {
      const int j = q - 2 + dt;
      if (0 <= j && j < NBINS) {
        const float kk[5] = {K0, K1, K2, K1, K0};
#pragma unroll
        for (int i = 0; i < 5; ++i) {
          int m = j - 2 + i;
          m = (m < 0) ? -m : m;
          m = (m > NBINS - 1) ? 2 * (NBINS - 1) - m : m;
          if (m == q) t += kk[i];
        }
      }
    }
    s_tab[idx] = t;
  }
  __syncthreads();

  const int wave = threadIdx.x >> 6;
  const int lane = threadIdx.x & 63;
  const int tid = blockIdx.x * TPB + threadIdx.x;   // == g*64+lane
  const int nthreads = nblocks * TPB;
  float num = 0.f;

  // --- all-DMA wave-private pipeline, 3 steps in flight -------------------
  // R3 post-mortem: a 3-deep ladder of 16B dwordx4 loads = 54 B/wave in
  // flight -> ~0.9 TB/s latency-bound (measured). global_load_lds moves
  // 1 KB per instruction per wave through the same ladder -> ~3 KB/wave in
  // flight; latency fully hidden. R0's 88us limiter was its OTHER (direct
  // nontemporal) half at 3x16B in flight -- that path is gone.
  unsigned qq[PIPE];
  int jj[PIPE];

  int cb = tid;                      // chunk index; +524,288 per step
  const int e0 = cb << 2;
  unsigned f = (unsigned)e0 / 50u;   // one division; then incremental walk
  int j0 = e0 - (int)f * 50;

  const int bulk = STEPS * nthreads;          // 6,291,456 chunks
  if (nvec >= bulk) {
    auto STAGE = [&](int b) {
      __builtin_amdgcn_global_load_lds(
          (const __attribute__((address_space(1))) void*)(const void*)(preds4 + cb),
          (__attribute__((address_space(3))) void*)(void*)&buf[b][wave * 64],
          16, 0, 0);
      qq[b] = qv2[f];                // global_load_ushort, same vmcnt group
      jj[b] = j0;
      cb += nthreads;
      j0 += DJ;
      const unsigned carry = (j0 >= NBINS) ? 1u : 0u;
      j0 = (j0 >= NBINS) ? j0 - NBINS : j0;
      f += (unsigned)DF + carry;
    };
    STAGE(0); STAGE(1); STAGE(2);
#pragma unroll
    for (int s = 0; s < STEPS; ++s) {
      const int b = s & 3;
      if (s + 3 < STEPS) {
        STAGE((s + 3) & 3);
        // 3 younger groups (6 vmem: 3 DMA + 3 ushort) in flight; group s done
        asm volatile("s_waitcnt vmcnt(6)" ::: "memory");
      } else if (s + 2 < STEPS) {
        asm volatile("s_waitcnt vmcnt(4)" ::: "memory");
      } else if (s + 1 < STEPS) {
        asm volatile("s_waitcnt vmcnt(2)" ::: "memory");
      } else {
        asm volatile("s_waitcnt vmcnt(0)" ::: "memory");
      }
      const vf4 p = buf[b][wave * 64 + lane];   // ds_read_b128, DMA-filled
      consume_chunk(p, qq[b], jj[b], s_tab, num);
    }
  }

  // vector remainder: 262,144 chunks at this shape (half the threads do 1)
  const int start = (nvec >= bulk) ? bulk : 0;
  for (int v = start + tid; v < nvec; v += nthreads) {
    const vf4 p = preds4[v];
    const int e = v << 2;
    const unsigned ff = (unsigned)e / 50u;
    consume_chunk(p, qv2[ff], e - (int)ff * 50, s_tab, num);
  }
  // scalar element tail (total % 4 != 0; empty at this shape)
  for (int e = (nvec << 2) + tid; e < total; e += nthreads) {
    const unsigned ff = (unsigned)e / 50u;
    const int j = e - (int)ff * 50;
    const unsigned c = qv2[ff] & 255u;
    const float x = ((const float*)preds4)[e];
    const unsigned qc = (c > 50u) ? 50u : c;
    int dj = j - (int)c + 3;
    dj = dj < 0 ? 0 : (dj > 7 ? 7 : dj);
    const float t = s_tab[(qc << 3) + dj];
    const float spv = (c != 255u) ? softplus_stable(x) : 0.f;
    num += __builtin_fmaf(-x, t, spv);
  }

  // wave-64 reduction, then one atomic per block
#pragma unroll
  for (int off = 32; off > 0; off >>= 1)
    num += __shfl_down(num, off, 64);
  __shared__ float sn[TPB / 64];
  if (lane == 0) sn[wave] = num;
  __syncthreads();
  if (threadIdx.x == 0) {
    const float n = sn[0] + sn[1] + sn[2] + sn[3];
    atomicAdd(&acc[0], n);
    __threadfence();
    const unsigned done = atomicAdd((unsigned*)&acc[2], 1u);
    if (done == (unsigned)nblocks - 1u) {
      const float tn = atomicAdd(&acc[0], 0.f);
      const unsigned nvalid = atomicAdd((unsigned*)&acc[1], 0u);
      out[0] = tn / (50.0f * (float)nvalid);
    }
  }
}

extern "C" void kernel_launch(void* const* d_in, const int* in_sizes, int n_in,
                              void* d_out, int out_size, void* d_ws, size_t ws_size,
                              hipStream_t stream) {
  const vf4* preds4 = (const vf4*)d_in[0];
  const int* gt = (const int*)d_in[1];
  float* out = (float*)d_out;
  float* acc = (float*)d_ws;                                   // 12 B
  unsigned short* qv2 = (unsigned short*)((char*)d_ws + 256);  // 1 MB
  const int total = in_sizes[0];     // 26214400
  const int nframes = in_sizes[1];   // 524288
  const int nvec = total >> 2;       // 6553600

  (void)hipMemsetAsync(acc, 0, 3 * sizeof(float), stream);

  pitch_pre<<<(nframes + 255) / 256, 256, 0, stream>>>(gt, qv2, nframes, acc);

  pitch_loss_main<<<GRID, TPB, 0, stream>>>(
      preds4, qv2, nvec, total, GRID, acc, out);
}

// Round 6
// 300.721 us; speedup vs baseline: 1.1378x; 1.0749x over previous
//
#include <hip/hip_runtime.h>

#define NBINS 50
#define PAD_G 100
#define TPB 256
#define TILE_CHUNKS 512   // float4 chunks per tile per block (8 KB)
#define GRID 1280
#define STEPS 10          // GRID*STEPS*TILE_CHUNKS == nvec exactly
#define PIPE 6            // LDS slots; 5 tiles in flight (R0 had 3)

typedef float vf4 __attribute__((ext_vector_type(4)));

// Gaussian kernel (5 taps, sigma=0.5), normalized
#define K0 2.6387004e-4f
#define K1 1.0645079e-1f
#define K2 7.8657085e-1f

__device__ __forceinline__ int quant(int g) {
  int d = g - 50;
  d = (d < 0) ? 0 : d;
  int q = __umul24((unsigned)d, 10923u) >> 16;  // exact /6 for this range
  return (q > NBINS - 1) ? (NBINS - 1) : q;
}

__device__ __forceinline__ float softplus_stable(float x) {
  return fmaxf(x, 0.f) + __logf(1.f + __expf(-fabsf(x)));
}

// qv2[f]: low byte = code(frame f), high byte = code(frame f+1); 255 = padded.
// Also accumulates #non-pad frames into acc[1] (mask.sum() == 50 * that).
__global__ __launch_bounds__(256) void pitch_pre(
    const int* __restrict__ gt, unsigned short* __restrict__ qv2, int n,
    float* __restrict__ acc)
{
  const int f = blockIdx.x * blockDim.x + threadIdx.x;
  if (f >= n) return;
  const int g0 = gt[f];
  const int f1 = (f + 1 < n) ? f + 1 : n - 1;
  const int g1 = gt[f1];
  const unsigned b0 = (g0 == PAD_G) ? 255u : (unsigned)quant(g0);
  const unsigned b1 = (g1 == PAD_G) ? 255u : (unsigned)quant(g1);
  qv2[f] = (unsigned short)(b0 | (b1 << 8));
  const unsigned long long ball = __ballot(g0 != PAD_G);
  if ((threadIdx.x & 63) == 0)
    atomicAdd((unsigned*)&acc[1], (unsigned)__popcll(ball));
}

// s_tab layout: 51 rows x 8 cols. Row q (q<50): col d1 holds the blur weight
// for output bin j = q - 2 + (d1-1); cols 0,6,7 are zero. Row 50 is all zero
// (absorbs pad code 255). Lookup: clamp(j - c + 3, 0, 7); out-of-range taps
// land on zero entries, no extra range compare needed.
__device__ __forceinline__ void consume_chunk(
    vf4 p, unsigned q2, int j0, const float* s_tab, float& num)
{
  const unsigned c0 = q2 & 255u;
  const unsigned c1 = (q2 >> 8) & 255u;
#pragma unroll
  for (int u = 0; u < 4; ++u) {
    int j = j0 + u;
    const bool wrap = (j >= NBINS);
    const unsigned c = wrap ? c1 : c0;
    j = wrap ? j - NBINS : j;
    const float x = p[u];
    const float sp = softplus_stable(x);
    const unsigned qc = (c > 50u) ? 50u : c;   // 255 -> zero row
    int dj = j - (int)c + 3;                   // tap offset +2, bias +1
    dj = dj < 0 ? 0 : (dj > 7 ? 7 : dj);
    const float t = s_tab[(qc << 3) + dj];
    const float spv = (c != 255u) ? sp : 0.f;  // pad frames contribute nothing
    num += __builtin_fmaf(-x, t, spv);
  }
}

__global__ __launch_bounds__(TPB, 5) void pitch_loss_main(
    const vf4* __restrict__ preds4,
    const unsigned short* __restrict__ qv2,
    int nvec, int total, int ntiles, int nblocks,
    float* __restrict__ acc,     // [0]=num(float) [1]=nvalid(uint) [2]=ctr(uint)
    float* __restrict__ out)
{
  __shared__ vf4 buf[PIPE][TILE_CHUNKS / 2];   // 6 x 4 KB (DMA half only)
  __shared__ float s_tab[51 * 8];

  for (int idx = threadIdx.x; idx < 51 * 8; idx += TPB) {
    const int q = idx >> 3;
    const int dt = (idx & 7) - 1;        // tap offset in [-1..6]; valid 0..4
    float t = 0.f;
    if (q < NBINS && 0 <= dt && dt < 5) {
      const int j = q - 2 + dt;
      if (0 <= j && j < NBINS) {
        const float kk[5] = {K0, K1, K2, K1, K0};
#pragma unroll
        for (int i = 0; i < 5; ++i) {
          int m = j - 2 + i;
          m = (m < 0) ? -m : m;
          m = (m > NBINS - 1) ? 2 * (NBINS - 1) - m : m;
          if (m == q) t += kk[i];
        }
      }
    }
    s_tab[idx] = t;
  }
  __syncthreads();

  const int wave = threadIdx.x >> 6;
  const int lane = threadIdx.x & 63;

  float num = 0.f;
  vf4 pr[PIPE];          // direct-nt half (VGPR path)
  unsigned uu[PIPE];     // two packed frame-code pairs per slot

  // R0's proven dual-path stage: per wave per tile, chunks [wave*128,+64)
  // via global_load_lds (1 KB/instr), chunks [+64,+128) via direct
  // nontemporal 16B loads. R2-R4 showed either path ALONE caps at
  // ~0.86 TB/s; only both together reached 1.19 TB/s. One variable
  // changed vs R0: 5 tiles in flight instead of 3.
  auto STAGE = [&](int t, int bb) {
    const int tc = (t < ntiles) ? t : ntiles - 1;   // exact fit: no-op clamp
    const int cb = tc * TILE_CHUNKS + wave * 128 + lane;
    __builtin_amdgcn_global_load_lds(
        (const __attribute__((address_space(1))) void*)(const void*)(preds4 + cb),
        (__attribute__((address_space(3))) void*)(void*)&buf[bb][wave * 64],
        16, 0, 0);
    pr[bb] = __builtin_nontemporal_load(preds4 + cb + 64);
    const unsigned f0 = (unsigned)(cb << 2) / 50u;           // magic-mul
    const unsigned f1 = (unsigned)((cb + 64) << 2) / 50u;
    const unsigned qa = qv2[f0];
    const unsigned qb = qv2[f1];
    uu[bb] = qa | (qb << 16);
  };

  auto COMPUTE = [&](int t, int bb) {
    const int tc = (t < ntiles) ? t : ntiles - 1;
    const int cb = tc * TILE_CHUNKS + wave * 128 + lane;
    const vf4 p0 = buf[bb][wave * 64 + lane];       // ds_read_b128
    const int e0 = cb << 2;
    const unsigned f0 = (unsigned)e0 / 50u;
    consume_chunk(p0, uu[bb] & 0xFFFFu, e0 - (int)f0 * 50, s_tab, num);
    const vf4 p1 = pr[bb];
    const int e1 = e0 + 256;
    const unsigned f1 = (unsigned)e1 / 50u;
    consume_chunk(p1, uu[bb] >> 16, e1 - (int)f1 * 50, s_tab, num);
  };

  // wave-private pipeline, 5 tiles in flight, no barriers in the loop.
  // Each STAGE = 4 vmem ops (DMA, direct, 2x ushort); all slot indices
  // compile-time (rule #20: runtime-indexed reg arrays go to scratch).
  STAGE(blockIdx.x,               0);
  STAGE(blockIdx.x + 1 * nblocks, 1);
  STAGE(blockIdx.x + 2 * nblocks, 2);
  STAGE(blockIdx.x + 3 * nblocks, 3);
  STAGE(blockIdx.x + 4 * nblocks, 4);
#pragma unroll
  for (int s = 0; s < STEPS; ++s) {
    const int bb = s % PIPE;
    if (s + 5 < STEPS) {
      STAGE(blockIdx.x + (s + 5) * nblocks, (s + 5) % PIPE);
      // 5 younger groups (20 vmem) in flight; group s drained
      asm volatile("s_waitcnt vmcnt(20)" ::: "memory");
    } else if (s + 4 < STEPS) {
      asm volatile("s_waitcnt vmcnt(16)" ::: "memory");
    } else if (s + 3 < STEPS) {
      asm volatile("s_waitcnt vmcnt(12)" ::: "memory");
    } else if (s + 2 < STEPS) {
      asm volatile("s_waitcnt vmcnt(8)" ::: "memory");
    } else if (s + 1 < STEPS) {
      asm volatile("s_waitcnt vmcnt(4)" ::: "memory");
    } else {
      asm volatile("s_waitcnt vmcnt(0)" ::: "memory");
    }
    COMPUTE(blockIdx.x + s * nblocks, bb);
  }

  // generic tails (empty at 26,214,400: exact fit, total%4==0)
  const int tid = blockIdx.x * TPB + threadIdx.x;
  const int nthreads = nblocks * TPB;
  for (int v = ntiles * TILE_CHUNKS + tid; v < nvec; v += nthreads) {
    const int e0 = v << 2;
    const unsigned f = (unsigned)e0 / 50u;
    const vf4 p = preds4[v];
    consume_chunk(p, qv2[f], e0 - (int)f * 50, s_tab, num);
  }
  for (int e = (nvec << 2) + tid; e < total; e += nthreads) {
    const unsigned f = (unsigned)e / 50u;
    const int j = e - (int)f * 50;
    const unsigned c = qv2[f] & 255u;
    const float x = ((const float*)preds4)[e];
    const unsigned qc = (c > 50u) ? 50u : c;
    int dj = j - (int)c + 3;
    dj = dj < 0 ? 0 : (dj > 7 ? 7 : dj);
    const float t = s_tab[(qc << 3) + dj];
    const float spv = (c != 255u) ? softplus_stable(x) : 0.f;
    num += __builtin_fmaf(-x, t, spv);
  }

  // wave-64 reduction, then one atomic per block
#pragma unroll
  for (int off = 32; off > 0; off >>= 1)
    num += __shfl_down(num, off, 64);
  __shared__ float sn[TPB / 64];
  if (lane == 0) sn[wave] = num;
  __syncthreads();
  if (threadIdx.x == 0) {
    const float n = sn[0] + sn[1] + sn[2] + sn[3];
    atomicAdd(&acc[0], n);
    __threadfence();
    const unsigned done = atomicAdd((unsigned*)&acc[2], 1u);
    if (done == (unsigned)nblocks - 1u) {
      const float tn = atomicAdd(&acc[0], 0.f);
      const unsigned nvalid = atomicAdd((unsigned*)&acc[1], 0u);
      out[0] = tn / (50.0f * (float)nvalid);
    }
  }
}

extern "C" void kernel_launch(void* const* d_in, const int* in_sizes, int n_in,
                              void* d_out, int out_size, void* d_ws, size_t ws_size,
                              hipStream_t stream) {
  const vf4* preds4 = (const vf4*)d_in[0];
  const int* gt = (const int*)d_in[1];
  float* out = (float*)d_out;
  float* acc = (float*)d_ws;                                   // 12 B
  unsigned short* qv2 = (unsigned short*)((char*)d_ws + 256);  // 1 MB
  const int total = in_sizes[0];     // 26214400
  const int nframes = in_sizes[1];   // 524288
  const int nvec = total >> 2;       // 6553600
  const int ntiles = nvec / TILE_CHUNKS;  // 12800 == GRID*STEPS

  (void)hipMemsetAsync(acc, 0, 3 * sizeof(float), stream);

  pitch_pre<<<(nframes + 255) / 256, 256, 0, stream>>>(gt, qv2, nframes, acc);

  pitch_loss_main<<<GRID, TPB, 0, stream>>>(
      preds4, qv2, nvec, total, ntiles, GRID, acc, out);
}

// Round 7
// 202.384 us; speedup vs baseline: 1.6907x; 1.4859x over previous
//
#include <hip/hip_runtime.h>

#define NBINS 50
#define PAD_G 100
#define TPB 256
#define TILE_CHUNKS 512   // float4 chunks per tile per block (8 KB)
#define GRID 1280
#define STEPS 10          // GRID*STEPS*TILE_CHUNKS == nvec exactly
#define PIPE 4            // LDS buffers; 3 tiles in flight (R0-proven)

typedef float vf4 __attribute__((ext_vector_type(4)));

// Gaussian kernel (5 taps, sigma=0.5), normalized
#define K0 2.6387004e-4f
#define K1 1.0645079e-1f
#define K2 7.8657085e-1f

__device__ __forceinline__ unsigned quant(int g) {
  int d = g - 50;
  d = (d < 0) ? 0 : d;
  unsigned q = __umul24((unsigned)d, 10923u) >> 16;  // exact /6 for this range
  return (q > NBINS - 1) ? (NBINS - 1) : q;
}

__device__ __forceinline__ float softplus_stable(float x) {
  return fmaxf(x, 0.f) + __logf(1.f + __expf(-fabsf(x)));
}

// qv2[f]: low byte = code(frame f), high byte = code(frame f+1); 255 = padded.
// R6 post-mortem: the R2-R6 version did one same-address atomicAdd per wave
// (8192 waves x ~12ns serialized across XCDs = 96us, was the top dispatch).
// Atomic-free again; the valid-element count lives in the main kernel
// (R0-proven free there). Vectorized: 4 frames/thread, int4 in, ushort4 out.
__global__ __launch_bounds__(256) void pitch_pre(
    const int* __restrict__ gt, unsigned short* __restrict__ qv2, int n)
{
  const int base = (blockIdx.x * blockDim.x + threadIdx.x) << 2;
  if (base >= n) return;
  if (base + 4 <= n) {
    const int4 g = *reinterpret_cast<const int4*>(gt + base);
    const int g4 = (base + 4 < n) ? gt[base + 4] : gt[n - 1];
    const unsigned c0 = (g.x == PAD_G) ? 255u : quant(g.x);
    const unsigned c1 = (g.y == PAD_G) ? 255u : quant(g.y);
    const unsigned c2 = (g.z == PAD_G) ? 255u : quant(g.z);
    const unsigned c3 = (g.w == PAD_G) ? 255u : quant(g.w);
    const unsigned c4 = (g4  == PAD_G) ? 255u : quant(g4);
    ushort4 o;
    o.x = (unsigned short)(c0 | (c1 << 8));
    o.y = (unsigned short)(c1 | (c2 << 8));
    o.z = (unsigned short)(c2 | (c3 << 8));
    o.w = (unsigned short)(c3 | (c4 << 8));
    *reinterpret_cast<ushort4*>(qv2 + base) = o;
  } else {
    for (int f = base; f < n; ++f) {           // generic tail (empty here)
      const int ga = gt[f];
      const int gb = gt[(f + 1 < n) ? f + 1 : n - 1];
      const unsigned ba = (ga == PAD_G) ? 255u : quant(ga);
      const unsigned bb = (gb == PAD_G) ? 255u : quant(gb);
      qv2[f] = (unsigned short)(ba | (bb << 8));
    }
  }
}

// s_tab layout: 51 rows x 8 cols. Row q (q<50): col d1 holds the blur weight
// for output bin j = q - 2 + (d1-1); cols 0,6,7 are zero. Row 50 is all zero
// (absorbs pad code 255). Lookup: clamp(j - c + 3, 0, 7); out-of-range taps
// land on zero entries -- saves the (dj<5) cmp+cndmask R0's 50x5 table needed.
__device__ __forceinline__ void consume_chunk(
    vf4 p, unsigned q2, int j0, const float* s_tab,
    float& num, unsigned& cnt)
{
  const unsigned c0 = q2 & 255u;
  const unsigned c1 = (q2 >> 8) & 255u;
#pragma unroll
  for (int u = 0; u < 4; ++u) {
    int j = j0 + u;
    const bool wrap = (j >= NBINS);
    const unsigned c = wrap ? c1 : c0;
    j = wrap ? j - NBINS : j;
    const float x = p[u];
    const float sp = softplus_stable(x);
    const unsigned qc = (c > 50u) ? 50u : c;   // 255 -> zero row
    int dj = j - (int)c + 3;                   // tap offset +2, bias +1
    dj = dj < 0 ? 0 : (dj > 7 ? 7 : dj);
    const float t = s_tab[(qc << 3) + dj];
    const bool valid = (c != 255u);
    num += valid ? __builtin_fmaf(-x, t, sp) : 0.f;
    cnt += valid ? 1u : 0u;
  }
}

__global__ __launch_bounds__(TPB) void pitch_loss_main(
    const vf4* __restrict__ preds4,
    const unsigned short* __restrict__ qv2,
    int nvec, int total, int ntiles, int nblocks,
    float* __restrict__ acc,     // [0]=num(float) [1]=cnt(uint) [2]=ctr(uint)
    float* __restrict__ out)
{
  __shared__ vf4 buf[PIPE][TILE_CHUNKS / 2];   // 4 x 4 KB (DMA half only)
  __shared__ float s_tab[51 * 8];

  for (int idx = threadIdx.x; idx < 51 * 8; idx += TPB) {
    const int q = idx >> 3;
    const int dt = (idx & 7) - 1;        // tap offset in [-1..6]; valid 0..4
    float t = 0.f;
    if (q < NBINS && 0 <= dt && dt < 5) {
      const int j = q - 2 + dt;
      if (0 <= j && j < NBINS) {
        const float kk[5] = {K0, K1, K2, K1, K0};
#pragma unroll
        for (int i = 0; i < 5; ++i) {
          int m = j - 2 + i;
          m = (m < 0) ? -m : m;
          m = (m > NBINS - 1) ? 2 * (NBINS - 1) - m : m;
          if (m == q) t += kk[i];
        }
      }
    }
    s_tab[idx] = t;
  }
  __syncthreads();

  const int wave = threadIdx.x >> 6;
  const int lane = threadIdx.x & 63;

  float num = 0.f;
  unsigned cnt = 0;
  vf4 pr[PIPE];                 // direct-nt half (VGPR path)
  unsigned uu[PIPE][2];         // staged frame-codes (compile-time indexed)

  // R0's proven dual-path stage: per wave per tile, chunks [wave*128,+64)
  // via global_load_lds (1 KB/instr), chunks [+64,+128) via direct
  // nontemporal 16B loads. Single-path variants (R3 direct-only, R4
  // DMA-only) both cap at ~0.86 TB/s; dual path measured 1.19 TB/s.
  // Depth 3 in flight (PIPE=4): R6 measured depth-5 at ~95us vs 88 -- keep 3.
  auto STAGE = [&](int t, int bb) {
    const int tc = (t < ntiles) ? t : ntiles - 1;   // exact fit: no-op clamp
    const int cb = tc * TILE_CHUNKS + wave * 128 + lane;
    __builtin_amdgcn_global_load_lds(
        (const __attribute__((address_space(1))) void*)(const void*)(preds4 + cb),
        (__attribute__((address_space(3))) void*)(void*)&buf[bb][wave * 64],
        16, 0, 0);
    pr[bb] = __builtin_nontemporal_load(preds4 + cb + 64);
    const unsigned f0 = (unsigned)(cb << 2) / 50u;           // magic-mul
    const unsigned f1 = (unsigned)((cb + 64) << 2) / 50u;
    const unsigned qa = qv2[f0];
    const unsigned qb = qv2[f1];
    uu[bb][0] = (t < ntiles) ? qa : 0xFFFFu;
    uu[bb][1] = (t < ntiles) ? qb : 0xFFFFu;
  };

  auto COMPUTE = [&](int t, int bb) {
    const int tc = (t < ntiles) ? t : ntiles - 1;
    const int cb = tc * TILE_CHUNKS + wave * 128 + lane;
    const vf4 p0 = buf[bb][wave * 64 + lane];       // ds_read_b128
    const int e0 = cb << 2;
    const unsigned f0 = (unsigned)e0 / 50u;
    consume_chunk(p0, uu[bb][0], e0 - (int)f0 * 50, s_tab, num, cnt);
    const vf4 p1 = pr[bb];
    const int e1 = e0 + 256;
    const unsigned f1 = (unsigned)e1 / 50u;
    consume_chunk(p1, uu[bb][1], e1 - (int)f1 * 50, s_tab, num, cnt);
  };

  // wave-private pipeline, 3 tiles in flight, no barriers in the loop.
  // STEPS and all bb indices are compile-time -> pr/uu stay in registers.
  STAGE(blockIdx.x, 0);
  STAGE(blockIdx.x + nblocks, 1);
  STAGE(blockIdx.x + 2 * nblocks, 2);
#pragma unroll
  for (int s = 0; s < STEPS; ++s) {
    const int bb = s & 3;
    if (s + 3 < STEPS) {
      STAGE(blockIdx.x + (s + 3) * nblocks, (s + 3) & 3);
      // 3 younger groups (12 vmem ops) in flight; group s drained
      asm volatile("s_waitcnt vmcnt(12)" ::: "memory");
    } else if (s + 2 < STEPS) {
      asm volatile("s_waitcnt vmcnt(8)" ::: "memory");
    } else if (s + 1 < STEPS) {
      asm volatile("s_waitcnt vmcnt(4)" ::: "memory");
    } else {
      asm volatile("s_waitcnt vmcnt(0)" ::: "memory");
    }
    COMPUTE(blockIdx.x + s * nblocks, bb);
  }

  // generic tails (empty at 26,214,400)
  const int tid = blockIdx.x * TPB + threadIdx.x;
  const int nthreads = nblocks * TPB;
  for (int v = ntiles * TILE_CHUNKS + tid; v < nvec; v += nthreads) {
    const int e0 = v << 2;
    const unsigned f = (unsigned)e0 / 50u;
    const vf4 p = preds4[v];
    consume_chunk(p, qv2[f], e0 - (int)f * 50, s_tab, num, cnt);
  }
  for (int e = (nvec << 2) + tid; e < total; e += nthreads) {
    const unsigned f = (unsigned)e / 50u;
    const int j = e - (int)f * 50;
    const unsigned c = qv2[f] & 255u;
    if (c != 255u) {
      const unsigned qc = (c > 50u) ? 50u : c;
      int dj = j - (int)c + 3;
      dj = dj < 0 ? 0 : (dj > 7 ? 7 : dj);
      const float t = s_tab[(qc << 3) + dj];
      const float x = ((const float*)preds4)[e];
      num += softplus_stable(x) - x * t;
      cnt += 1u;
    }
  }

  // wave-64 reduction, then one atomic per block
#pragma unroll
  for (int off = 32; off > 0; off >>= 1) {
    num += __shfl_down(num, off, 64);
    cnt += __shfl_down(cnt, off, 64);
  }
  __shared__ float sn[4];
  __shared__ unsigned sc[4];
  if (lane == 0) { sn[wave] = num; sc[wave] = cnt; }
  __syncthreads();
  if (threadIdx.x == 0) {
    const float n = sn[0] + sn[1] + sn[2] + sn[3];
    const unsigned cc = sc[0] + sc[1] + sc[2] + sc[3];
    atomicAdd(&acc[0], n);
    atomicAdd((unsigned*)&acc[1], cc);
    __threadfence();
    const unsigned done = atomicAdd((unsigned*)&acc[2], 1u);
    if (done == (unsigned)nblocks - 1u) {
      const float tn = atomicAdd(&acc[0], 0.f);
      const unsigned tc = atomicAdd((unsigned*)&acc[1], 0u);
      out[0] = tn / (float)tc;
    }
  }
}

extern "C" void kernel_launch(void* const* d_in, const int* in_sizes, int n_in,
                              void* d_out, int out_size, void* d_ws, size_t ws_size,
                              hipStream_t stream) {
  const vf4* preds4 = (const vf4*)d_in[0];
  const int* gt = (const int*)d_in[1];
  float* out = (float*)d_out;
  float* acc = (float*)d_ws;                                   // 12 B
  unsigned short* qv2 = (unsigned short*)((char*)d_ws + 256);  // 1 MB
  const int total = in_sizes[0];     // 26214400
  const int nframes = in_sizes[1];   // 524288
  const int nvec = total >> 2;       // 6553600
  const int ntiles = nvec / TILE_CHUNKS;  // 12800 == GRID*STEPS

  (void)hipMemsetAsync(acc, 0, 3 * sizeof(float), stream);

  const int pre_groups = (nframes + 3) >> 2;
  pitch_pre<<<(pre_groups + 255) / 256, 256, 0, stream>>>(gt, qv2, nframes);

  pitch_loss_main<<<GRID, TPB, 0, stream>>>(
      preds4, qv2, nvec, total, ntiles, GRID, acc, out);
}